// Round 7
// baseline (270.079 us; speedup 1.0000x reference)
//
#include <hip/hip_runtime.h>
#include <hip/hip_bf16.h>
#include <stdint.h>

// Problem constants (B,T,D,NH from reference)
#define NHh 16
#define Dm  1024
#define HD  64          // head dim = D/NH
#define Bb  4
#define Tt  4096
#define NCH 128         // chunks along T for the two-pass scans
#define CHL 32          // chunk length (NCH*CHL == Tt)

// 256x256 GEMM tile geometry
#define BM 256
#define BN 256
#define BK 64
#define NKT (Dm / BK)   // 16 K-tiles

using bf16 = __hip_bfloat16;
typedef __attribute__((ext_vector_type(8))) short short8;   // 8 bf16 in 4 VGPRs (MFMA A/B frag)
typedef __attribute__((ext_vector_type(4))) float f32x4;    // MFMA C/D frag

__device__ __forceinline__ float bf2f(bf16 v) { return __bfloat162float(v); }

// bf16 bits -> f32 (exact): bf16 is the high 16 bits of f32
__device__ __forceinline__ float b2f(unsigned short u) {
  union { unsigned int i; float f; } x; x.i = ((unsigned int)u) << 16; return x.f;
}

// fast reciprocal via v_rcp_f32 (~1 ulp; inputs are bf16-derived, tolerance is 1e-2)
__device__ __forceinline__ float frcp(float x) {
  float r; asm("v_rcp_f32 %0, %1" : "=v"(r) : "v"(x)); return r;
}

// async global->LDS, 16B per lane. LDS dest is wave-uniform base + lane*16.
__device__ __forceinline__ void gld_lds16(const void* g, void* l) {
  __builtin_amdgcn_global_load_lds(
      (const __attribute__((address_space(1))) unsigned int*)g,
      (__attribute__((address_space(3))) unsigned int*)l, 16, 0, 0);
}

__device__ __forceinline__ short8 pack8(const float4& a, const float4& b) {
  short8 r;
  r[0] = (short)__bfloat16_as_ushort(__float2bfloat16(a.x));
  r[1] = (short)__bfloat16_as_ushort(__float2bfloat16(a.y));
  r[2] = (short)__bfloat16_as_ushort(__float2bfloat16(a.z));
  r[3] = (short)__bfloat16_as_ushort(__float2bfloat16(a.w));
  r[4] = (short)__bfloat16_as_ushort(__float2bfloat16(b.x));
  r[5] = (short)__bfloat16_as_ushort(__float2bfloat16(b.y));
  r[6] = (short)__bfloat16_as_ushort(__float2bfloat16(b.z));
  r[7] = (short)__bfloat16_as_ushort(__float2bfloat16(b.w));
  return r;
}

// ============== 256x256 GEMM, counted-vmcnt 2-phase pipeline =================
// C[m][n] = sum_k A[m][k] * W[n][k]  (K-contiguous row-major; W bf16).
// A_FP32: A is fp32 — reg-staged (8x global_load_dwordx4 issued in P1, cvt +
//   ds_write_b128 at P2 entry after vmcnt(2)); same LDS bytes as the gld_lds
//   path (global source is already inverse-swizzled). Ledger: P1 issues
//   8A+2B -> end-P1 vmcnt(10) retires prev-P2's 2 B slabs; P2-entry vmcnt(2)
//   retires the 8 A loads; end-P2 vmcnt(2)+lgkmcnt(0) retires this-P1's B
//   slabs and drains the A ds_writes before the barrier.
// !A_FP32: A bf16 via gld_lds (counts 6/2 as before).
// OUT_BF16: C staged in LDS post-loop (smem is dead) and copied out with
//   16B/lane coalesced stores — fixes the 2x HBM write amplification of the
//   32B-segment direct stores (measured WRITE 70 MB vs 34 ideal).
// WRITE_S1: fuse per-32-row chunk sums of bf16(w)^2 into the epilogue.
template <bool A_FP32, bool OUT_BF16, bool WRITE_S1>
__global__ __launch_bounds__(512, 2) void gemm256(const void* __restrict__ Ain,
                                                  const bf16* __restrict__ W,
                                                  void* __restrict__ Cout,
                                                  float* __restrict__ S1,
                                                  int M, int N, int K) {
  extern __shared__ char smem[];   // 131072 B: [buf][A 32K | B 32K]
  const int tid  = threadIdx.x;
  const int lane = tid & 63;
  const int wave = tid >> 6;       // 0..7
  // T1 XCD swizzle: 256 blocks = 8 XCDs x 32; consecutive swz share the A-panel
  const int bid = blockIdx.x;
  const int swz = (bid & 7) * 32 + (bid >> 3);
  const int bn = (swz & 3) * BN;          // N/BN = 4
  const int bm = (swz >> 2) * BM;
  const int wm = (wave >> 1) * 64;        // 4 M bands of 64 rows
  const int wn = (wave & 1) * 128;        // 2 N halves of 128 cols
  const int quad = lane >> 4;
  const int l16  = lane & 15;

  // staging source (per lane, per slab n): inverse-swizzled global address
  const int srow = wave * 8 + (lane >> 3);               // + n*64
  const int scol = (((lane & 7) ^ (lane >> 3)) << 3);    // elements

  const bf16*  Abase  = A_FP32 ? nullptr : ((const bf16*)Ain + (size_t)(bm + srow) * K + scol);
  const float* Afbase = A_FP32 ? ((const float*)Ain + (size_t)(bm + srow) * K + scol) : nullptr;
  const bf16*  Wbase  = W + (size_t)(bn + srow) * K + scol;

  f32x4 acc[4][8] = {};
  float4 aL[4][2];   // in-flight fp32 A (static-indexed via unrolled macros)

#define SLAB_A(buf, n) (smem + (buf) * 65536 + (n) * 8192 + wave * 1024)
#define SLAB_B(buf, n) (smem + (buf) * 65536 + 32768 + (n) * 8192 + wave * 1024)
#define STAGE_A(buf, n, k0) gld_lds16(Abase + (size_t)(n) * 64 * K + (k0), SLAB_A(buf, n))
#define STAGE_B(buf, n, k0) gld_lds16(Wbase + (size_t)(n) * 64 * K + (k0), SLAB_B(buf, n))
#define LOADA(n, k0) do {                                                    \
    const float* p_ = Afbase + (size_t)(n) * 64 * K + (k0);                  \
    aL[n][0] = *(const float4*)p_;                                           \
    aL[n][1] = *(const float4*)(p_ + 4);                                     \
  } while (0)
#define WRITEA(buf, n) do {                                                  \
    *(short8*)(SLAB_A(buf, n) + lane * 16) = pack8(aL[n][0], aL[n][1]);      \
  } while (0)
#define LD_FRAG(base, r, s) (*(const short8*)((base) + (size_t)(r) * 128 + ((((s) ^ ((r) & 7))) << 4)))

  // prologue: stage tile 0 fully into buf 0
  if constexpr (A_FP32) {
    LOADA(0, 0); LOADA(1, 0); LOADA(2, 0); LOADA(3, 0);
    STAGE_B(0, 0, 0); STAGE_B(0, 1, 0); STAGE_B(0, 2, 0); STAGE_B(0, 3, 0);
    asm volatile("s_waitcnt vmcnt(4)" ::: "memory");   // A loads landed
    WRITEA(0, 0); WRITEA(0, 1); WRITEA(0, 2); WRITEA(0, 3);
    asm volatile("s_waitcnt vmcnt(0) lgkmcnt(0)" ::: "memory");
  } else {
    STAGE_A(0, 0, 0); STAGE_A(0, 1, 0); STAGE_A(0, 2, 0); STAGE_A(0, 3, 0);
    STAGE_B(0, 0, 0); STAGE_B(0, 1, 0); STAGE_B(0, 2, 0); STAGE_B(0, 3, 0);
    asm volatile("s_waitcnt vmcnt(0)" ::: "memory");
  }
  __builtin_amdgcn_s_barrier();
  __builtin_amdgcn_sched_barrier(0);

  short8 af[4][2], bfv[4][2];
  for (int t = 0; t < NKT; t++) {
    const int buf = t & 1;
    const char* aLd = smem + buf * 65536;
    const char* bLd = aLd + 32768;
    const int k0n = (t + 1) * BK;
    const bool pf = (t + 1 < NKT);

    // ---- P1: issue A(t+1) (regs or gld_lds) + B0,B2(t+1); read A-all + B
    //      lower-halves of tile t; MFMA nj 0-3
    if (pf) {
      if constexpr (A_FP32) { LOADA(0, k0n); LOADA(1, k0n); LOADA(2, k0n); LOADA(3, k0n); }
      else { STAGE_A(buf ^ 1, 0, k0n); STAGE_A(buf ^ 1, 1, k0n);
             STAGE_A(buf ^ 1, 2, k0n); STAGE_A(buf ^ 1, 3, k0n); }
      STAGE_B(buf ^ 1, 0, k0n); STAGE_B(buf ^ 1, 2, k0n);
    }
#pragma unroll
    for (int mi = 0; mi < 4; mi++) {
      const int r = wm + mi * 16 + l16;
      af[mi][0] = LD_FRAG(aLd, r, quad);
      af[mi][1] = LD_FRAG(aLd, r, quad + 4);
    }
#pragma unroll
    for (int nj = 0; nj < 4; nj++) {
      const int r = wn + nj * 16 + l16;
      bfv[nj][0] = LD_FRAG(bLd, r, quad);
      bfv[nj][1] = LD_FRAG(bLd, r, quad + 4);
    }
    __builtin_amdgcn_s_setprio(1);
#pragma unroll
    for (int mi = 0; mi < 4; mi++)
#pragma unroll
      for (int nj = 0; nj < 4; nj++) {
        acc[mi][nj] = __builtin_amdgcn_mfma_f32_16x16x32_bf16(af[mi][0], bfv[nj][0], acc[mi][nj], 0, 0, 0);
        acc[mi][nj] = __builtin_amdgcn_mfma_f32_16x16x32_bf16(af[mi][1], bfv[nj][1], acc[mi][nj], 0, 0, 0);
      }
    __builtin_amdgcn_s_setprio(0);
    if (pf) {
      if constexpr (A_FP32) { asm volatile("s_waitcnt vmcnt(10)" ::: "memory"); }
      else                  { asm volatile("s_waitcnt vmcnt(6)" ::: "memory"); }
    } else { asm volatile("s_waitcnt vmcnt(0)" ::: "memory"); }
    __builtin_amdgcn_s_barrier();
    __builtin_amdgcn_sched_barrier(0);

    // ---- P2: (A_FP32) retire A loads + ds_write A(t+1); read B upper-halves;
    //      issue B1,B3(t+1); MFMA nj 4-7
    if (pf) {
      if constexpr (A_FP32) {
        asm volatile("s_waitcnt vmcnt(2)" ::: "memory");   // 8 A loads landed
        WRITEA(buf ^ 1, 0); WRITEA(buf ^ 1, 1); WRITEA(buf ^ 1, 2); WRITEA(buf ^ 1, 3);
      }
    }
#pragma unroll
    for (int nj = 0; nj < 4; nj++) {
      const int r = wn + 64 + nj * 16 + l16;
      bfv[nj][0] = LD_FRAG(bLd, r, quad);
      bfv[nj][1] = LD_FRAG(bLd, r, quad + 4);
    }
    if (pf) { STAGE_B(buf ^ 1, 1, k0n); STAGE_B(buf ^ 1, 3, k0n); }
    __builtin_amdgcn_s_setprio(1);
#pragma unroll
    for (int mi = 0; mi < 4; mi++)
#pragma unroll
      for (int nj = 0; nj < 4; nj++) {
        acc[mi][nj + 4] = __builtin_amdgcn_mfma_f32_16x16x32_bf16(af[mi][0], bfv[nj][0], acc[mi][nj + 4], 0, 0, 0);
        acc[mi][nj + 4] = __builtin_amdgcn_mfma_f32_16x16x32_bf16(af[mi][1], bfv[nj][1], acc[mi][nj + 4], 0, 0, 0);
      }
    __builtin_amdgcn_s_setprio(0);
    if (pf) { asm volatile("s_waitcnt vmcnt(2) lgkmcnt(0)" ::: "memory"); }
    else    { asm volatile("s_waitcnt vmcnt(0) lgkmcnt(0)" ::: "memory"); }
    __builtin_amdgcn_s_barrier();
    __builtin_amdgcn_sched_barrier(0);
  }

  // ============ epilogue.  C/D layout: col = lane&15, row = (lane>>4)*4 + reg
  if constexpr (OUT_BF16) {
    // stage C-tile in LDS (smem dead after loop).  Byte addr with 16B-chunk
    // XOR swizzle to spread the 2B scatter writes across banks:
    //   byte = row*512 + ((col*2) ^ ((row&7)<<4))
    ushort* cst = (ushort*)smem;
#pragma unroll
    for (int nj = 0; nj < 8; nj++) {
      const int gcol = bn + wn + nj * 16 + l16;
      float ss0 = 0.f, ss1 = 0.f;
#pragma unroll
      for (int mi = 0; mi < 4; mi++) {
        float csum = 0.f;
#pragma unroll
        for (int r = 0; r < 4; r++) {
          const int row = wm + mi * 16 + quad * 4 + r;          // tile-local
          const int col = wn + nj * 16 + l16;                   // tile-local
          const bf16 hv = __float2bfloat16(acc[mi][nj][r]);
          cst[(row * 512 + ((col * 2) ^ ((row & 7) << 4))) >> 1] = __bfloat16_as_ushort(hv);
          if constexpr (WRITE_S1) { const float fv = bf2f(hv); csum += fv * fv; }
        }
        if constexpr (WRITE_S1) { if (mi < 2) ss0 += csum; else ss1 += csum; }
      }
      if constexpr (WRITE_S1) {
        ss0 += __shfl_xor(ss0, 16, 64); ss0 += __shfl_xor(ss0, 32, 64);
        ss1 += __shfl_xor(ss1, 16, 64); ss1 += __shfl_xor(ss1, 32, 64);
        if (quad == 0) {
          const int h = gcol >> 6, d = gcol & 63;
          const int r0 = bm + wm;                    // first row of this wave's band
          const int b  = r0 >> 12;                   // / Tt
          const int c0 = (r0 & (Tt - 1)) >> 5;       // / CHL (=32)
          float* s1p = S1 + (((size_t)(b * NHh + h) * NCH) + c0) * HD + d;
          s1p[0]  = ss0;
          s1p[HD] = ss1;
        }
      }
    }
    asm volatile("s_waitcnt lgkmcnt(0)" ::: "memory");
    __builtin_amdgcn_s_barrier();
    // coalesced copy out: 512 threads x 16B, 16 iters = 128 KB
#pragma unroll
    for (int it = 0; it < 16; it++) {
      const int idx = it * 512 + tid;      // 16B-chunk id (8192 total)
      const int row = idx >> 5;            // 32 chunks per 512B row
      const int ch  = idx & 31;
      const short8 v = *(const short8*)(smem + row * 512 + ((ch ^ (row & 7)) << 4));
      *(short8*)((bf16*)Cout + (size_t)(bm + row) * N + bn + ch * 8) = v;
    }
  } else {
#pragma unroll
    for (int nj = 0; nj < 8; nj++) {
      const int col = bn + wn + nj * 16 + l16;
#pragma unroll
      for (int mi = 0; mi < 4; mi++)
#pragma unroll
        for (int r = 0; r < 4; r++) {
          const int row = bm + wm + mi * 16 + quad * 4 + r;
          ((float*)Cout)[(size_t)row * N + col] = acc[mi][nj][r];
        }
    }
  }
#undef SLAB_A
#undef SLAB_B
#undef STAGE_A
#undef STAGE_B
#undef LOADA
#undef WRITEA
#undef LD_FRAG
}

// ===== prep: fused {cast W_attn, cast W_proj, phi->penalty} (x cast is fused
// into gemm1's A staging now) =================================================
__global__ __launch_bounds__(256) void prep(const float* __restrict__ Wa,
                                            const float* __restrict__ Wp,
                                            const float* __restrict__ phi,
                                            bf16* __restrict__ Wa_bf,
                                            bf16* __restrict__ Wp_bf,
                                            float* __restrict__ penalty) {
  const int bid = blockIdx.x;
  if (bid < 512) {
    const float* in = (bid < 256) ? Wa : Wp;
    bf16* out = (bid < 256) ? Wa_bf : Wp_bf;
    const int b0 = (bid < 256) ? 0 : 256;
    const int n = Dm * Dm;
    const int stride = 256 * 256;
    for (int i = (bid - b0) * 256 + threadIdx.x; i * 4 < n; i += stride) {
      const float4 v = *(const float4*)(in + (size_t)i * 4);
      ushort4 o;
      o.x = __bfloat16_as_ushort(__float2bfloat16(v.x));
      o.y = __bfloat16_as_ushort(__float2bfloat16(v.y));
      o.z = __bfloat16_as_ushort(__float2bfloat16(v.z));
      o.w = __bfloat16_as_ushort(__float2bfloat16(v.w));
      *(ushort4*)(out + (size_t)i * 4) = o;
    }
  } else {
    const int b = bid - 512;
    const int tid = threadIdx.x;            // 256
    const int lane = tid & 63, wid = tid >> 6;
    __shared__ float wsum[4];
    __shared__ float carry_s;
    if (tid == 0) carry_s = 0.f;
    __syncthreads();
    for (int r = 0; r < Tt / 256; r++) {
      const int t = r * 256 + tid;
      const float v = phi[b * Tt + t];
      float incl = v;
#pragma unroll
      for (int off = 1; off < 64; off <<= 1) {
        float nn = __shfl_up(incl, off, 64);
        if (lane >= off) incl += nn;
      }
      if (lane == 63) wsum[wid] = incl;
      __syncthreads();
      float woff = carry_s;
      for (int wpre = 0; wpre < wid; wpre++) woff += wsum[wpre];
      const float csum = woff + incl;
      const float mean = csum / (float)(t + 1);
      const float dphi = v - mean;
      penalty[b * Tt + t] = dphi * dphi;
      __syncthreads();
      if (tid == 0) carry_s += wsum[0] + wsum[1] + wsum[2] + wsum[3];
      __syncthreads();
    }
  }
}

// ===== fused middle: inline S1 prefix -> tssa -> softmax(heads) -> dots sums =
__global__ __launch_bounds__(256) void mid_fused(const bf16* __restrict__ w,
                                                 const float* __restrict__ S1,
                                                 const float* __restrict__ temp,
                                                 const float* __restrict__ gamma,
                                                 const float* __restrict__ penalty,
                                                 float* __restrict__ alpha_f,
                                                 float* __restrict__ S2,
                                                 float* __restrict__ SA) {
  const int c = blockIdx.x, b = blockIdx.y;
  const int tid = threadIdx.x, h = tid >> 4, l = tid & 15;
  __shared__ float sm_t[CHL][NHh + 1];
  __shared__ float sm_a[CHL][NHh + 1];
  __shared__ float sm_g[NHh], sm_tv[NHh];
  if (tid < NHh) { sm_g[tid] = gamma[tid]; sm_tv[tid] = temp[tid]; }

  // inline exclusive prefix of S1 over chunks < c, 4-deep ILP
  const float4* p4 = (const float4*)(S1 + (((size_t)(b * NHh + h) * NCH)) * HD + l * 4);
  float4 s0 = {0,0,0,0}, s1v = {0,0,0,0}, s2v = {0,0,0,0}, s3v = {0,0,0,0};
  int cc = 0;
  for (; cc + 4 <= c; cc += 4) {
    const float4 v0 = p4[(size_t)cc * 16];
    const float4 v1 = p4[(size_t)(cc + 1) * 16];
    const float4 v2 = p4[(size_t)(cc + 2) * 16];
    const float4 v3 = p4[(size_t)(cc + 3) * 16];
    s0.x += v0.x; s0.y += v0.y; s0.z += v0.z; s0.w += v0.w;
    s1v.x += v1.x; s1v.y += v1.y; s1v.z += v1.z; s1v.w += v1.w;
    s2v.x += v2.x; s2v.y += v2.y; s2v.z += v2.z; s2v.w += v2.w;
    s3v.x += v3.x; s3v.y += v3.y; s3v.z += v3.z; s3v.w += v3.w;
  }
  for (; cc < c; cc++) {
    const float4 v0 = p4[(size_t)cc * 16];
    s0.x += v0.x; s0.y += v0.y; s0.z += v0.z; s0.w += v0.w;
  }
  float a0 = s0.x + s1v.x + s2v.x + s3v.x;
  float a1 = s0.y + s1v.y + s2v.y + s3v.y;
  float a2 = s0.z + s1v.z + s2v.z + s3v.z;
  float a3 = s0.w + s1v.w + s2v.w + s3v.w;
  __syncthreads();   // sm_g/sm_tv ready

  const bf16* wp = w + ((size_t)(b * Tt + c * CHL)) * Dm + h * HD + l * 4;
  const float tv = sm_tv[h];
#pragma unroll 8
  for (int i = 0; i < CHL; i++) {
    const ushort4 v = *(const ushort4*)(wp + (size_t)i * Dm);
    const float f0 = b2f(v.x), f1 = b2f(v.y), f2 = b2f(v.z), f3 = b2f(v.w);
    const float q0 = f0 * f0, q1 = f1 * f1, q2 = f2 * f2, q3 = f3 * f3;
    a0 += q0; a1 += q1; a2 += q2; a3 += q3;
    float val = q0 * frcp(fmaxf(a0, 1e-12f)) + q1 * frcp(fmaxf(a1, 1e-12f))
              + q2 * frcp(fmaxf(a2, 1e-12f)) + q3 * frcp(fmaxf(a3, 1e-12f));
    val += __shfl_xor(val, 1, 64);
    val += __shfl_xor(val, 2, 64);
    val += __shfl_xor(val, 4, 64);
    val += __shfl_xor(val, 8, 64);
    if (l == 0) sm_t[i][h] = tv * val;
  }
  __syncthreads();

  if (tid < CHL) {
    const int t = tid;
    const float pen = penalty[(size_t)b * Tt + c * CHL + t];
    float sc[NHh];
    float mx = -1e30f;
#pragma unroll
    for (int hh = 0; hh < NHh; hh++) {
      sc[hh] = sm_t[t][hh] - sm_g[hh] * pen;
      mx = fmaxf(mx, sc[hh]);
    }
    float sum = 0.f;
#pragma unroll
    for (int hh = 0; hh < NHh; hh++) { const float e = __expf(sc[hh] - mx); sc[hh] = e; sum += e; }
    const float inv = 1.f / sum;
#pragma unroll
    for (int hh = 0; hh < NHh; hh++) sm_a[t][hh] = sc[hh] * inv;
  }
  __syncthreads();

#pragma unroll
  for (int k2 = 0; k2 < CHL / 16; k2++) {
    const int t = k2 * 16 + l;
    alpha_f[((size_t)(b * NHh + h)) * Tt + c * CHL + t] = sm_a[t][h];
  }

  float d0 = 0.f, d1 = 0.f, d2 = 0.f, d3 = 0.f, sa = 0.f;
#pragma unroll 8
  for (int i = 0; i < CHL; i++) {
    const float a = sm_a[i][h];
    const ushort4 v = *(const ushort4*)(wp + (size_t)i * Dm);
    const float f0 = b2f(v.x), f1 = b2f(v.y), f2 = b2f(v.z), f3 = b2f(v.w);
    d0 += f0 * f0 * a; d1 += f1 * f1 * a; d2 += f2 * f2 * a; d3 += f3 * f3 * a;
    sa += a;
  }
  float4 o; o.x = d0; o.y = d1; o.z = d2; o.w = d3;
  *(float4*)&S2[(((size_t)(b * NHh + h) * NCH) + c) * HD + l * 4] = o;
  if (l == 0) SA[(size_t)(b * NHh + h) * NCH + c] = sa;
}

// ===== y': full-row blocks. grid (NCH, Bb), 256 threads = 16 heads x 16 lanes.
__global__ __launch_bounds__(256) void y_phase3(const bf16* __restrict__ w,
                                                const float* __restrict__ alpha_f,
                                                const float* __restrict__ S2,
                                                const float* __restrict__ SA,
                                                bf16* __restrict__ yprime) {
  const int c = blockIdx.x, b = blockIdx.y;
  const int tid = threadIdx.x, h = tid >> 4, l = tid & 15;

  // SA exclusive prefix over chunks < c: lanes split + shfl reduce
  const float* sap = SA + (size_t)(b * NHh + h) * NCH;
  float sa_part = 0.f;
  for (int cc = l; cc < c; cc += 16) sa_part += sap[cc];
  sa_part += __shfl_xor(sa_part, 1, 64);
  sa_part += __shfl_xor(sa_part, 2, 64);
  sa_part += __shfl_xor(sa_part, 4, 64);
  sa_part += __shfl_xor(sa_part, 8, 64);
  float acca = sa_part;   // uniform within the 16-lane group

  // S2 exclusive prefix over chunks < c (own 4 columns), 4-deep ILP
  const float4* p4 = (const float4*)(S2 + (((size_t)(b * NHh + h) * NCH)) * HD + l * 4);
  float4 s0 = {0,0,0,0}, s1v = {0,0,0,0}, s2v = {0,0,0,0}, s3v = {0,0,0,0};
  int cc = 0;
  for (; cc + 4 <= c; cc += 4) {
    const float4 v0 = p4[(size_t)cc * 16];
    const float4 v1 = p4[(size_t)(cc + 1) * 16];
    const float4 v2 = p4[(size_t)(cc + 2) * 16];
    const float4 v3 = p4[(size_t)(cc + 3) * 16];
    s0.x += v0.x; s0.y += v0.y; s0.z += v0.z; s0.w += v0.w;
    s1v.x += v1.x; s1v.y += v1.y; s1v.z += v1.z; s1v.w += v1.w;
    s2v.x += v2.x; s2v.y += v2.y; s2v.z += v2.z; s2v.w += v2.w;
    s3v.x += v3.x; s3v.y += v3.y; s3v.z += v3.z; s3v.w += v3.w;
  }
  for (; cc < c; cc++) {
    const float4 v0 = p4[(size_t)cc * 16];
    s0.x += v0.x; s0.y += v0.y; s0.z += v0.z; s0.w += v0.w;
  }
  float a0 = s0.x + s1v.x + s2v.x + s3v.x;
  float a1 = s0.y + s1v.y + s2v.y + s3v.y;
  float a2 = s0.z + s1v.z + s2v.z + s3v.z;
  float a3 = s0.w + s1v.w + s2v.w + s3v.w;

  const bf16* wp = w + ((size_t)(b * Tt + c * CHL)) * Dm + h * HD + l * 4;
  const float* ap = alpha_f + (size_t)(b * NHh + h) * Tt + c * CHL;
  bf16* yp = yprime + ((size_t)(b * Tt + c * CHL)) * Dm + h * HD + l * 4;
#pragma unroll 8
  for (int i = 0; i < CHL; i++) {
    const float a = ap[i];
    const ushort4 v = *(const ushort4*)(wp + (size_t)i * Dm);
    const float f0 = b2f(v.x), f1 = b2f(v.y), f2 = b2f(v.z), f3 = b2f(v.w);
    a0 += f0 * f0 * a; a1 += f1 * f1 * a; a2 += f2 * f2 * a; a3 += f3 * f3 * a;
    acca += a;
    const float rinv = frcp(acca + 1e-8f);
    const float at0 = fminf(frcp(1.f + a0 * rinv), 10000.f);
    const float at1 = fminf(frcp(1.f + a1 * rinv), 10000.f);
    const float at2 = fminf(frcp(1.f + a2 * rinv), 10000.f);
    const float at3 = fminf(frcp(1.f + a3 * rinv), 10000.f);
    ushort4 o;
    o.x = __bfloat16_as_ushort(__float2bfloat16(-f0 * a * at0));
    o.y = __bfloat16_as_ushort(__float2bfloat16(-f1 * a * at1));
    o.z = __bfloat16_as_ushort(__float2bfloat16(-f2 * a * at2));
    o.w = __bfloat16_as_ushort(__float2bfloat16(-f3 * a * at3));
    *(ushort4*)(yp + (size_t)i * Dm) = o;
  }
}

extern "C" void kernel_launch(void* const* d_in, const int* in_sizes, int n_in,
                              void* d_out, int out_size, void* d_ws, size_t ws_size,
                              hipStream_t stream) {
  const float* x     = (const float*)d_in[0];
  const float* phi   = (const float*)d_in[1];
  const float* Wattn = (const float*)d_in[2];
  const float* Wproj = (const float*)d_in[3];
  const float* gamma = (const float*)d_in[4];
  const float* temp  = (const float*)d_in[5];

  float* y_out    = (float*)d_out;                          // (B,T,D) fp32
  float* alpha_f  = y_out + (size_t)Bb * Tt * Dm;           // (B,NH,T) fp32

  char* ws = (char*)d_ws;
  bf16*  Wa_bf  = (bf16*)ws;  ws += (size_t)Dm * Dm * 2;              // 2 MB
  bf16*  Wp_bf  = (bf16*)ws;  ws += (size_t)Dm * Dm * 2;              // 2 MB
  bf16*  w_bf   = (bf16*)ws;  ws += (size_t)Bb * Tt * Dm * 2;         // 32 MB
  bf16*  yprime = (bf16*)ws;  ws += (size_t)Bb * Tt * Dm * 2;         // 32 MB
  float* pen    = (float*)ws; ws += (size_t)Bb * Tt * 4;              // 64 KB
  float* S1     = (float*)ws; ws += (size_t)Bb * NHh * NCH * HD * 4;  // 2 MB (raw)
  float* S2     = (float*)ws; ws += (size_t)Bb * NHh * NCH * HD * 4;  // 2 MB (raw)
  float* SA     = (float*)ws; ws += (size_t)Bb * NHh * NCH * 4;       // 32 KB (raw)

  static int attr_done = 0;
  if (!attr_done) {
    hipFuncSetAttribute((const void*)gemm256<true, true, true>,
                        hipFuncAttributeMaxDynamicSharedMemorySize, 131072);
    hipFuncSetAttribute((const void*)gemm256<false, false, false>,
                        hipFuncAttributeMaxDynamicSharedMemorySize, 131072);
    attr_done = 1;
  }

  const int M = Bb * Tt, N = Dm, K = Dm;
  dim3 gg((M / BM) * (N / BN)), gb(512);

  prep<<<dim3(516), dim3(256), 0, stream>>>(Wattn, Wproj, phi, Wa_bf, Wp_bf, pen);
  gemm256<true, true, true><<<gg, gb, 131072, stream>>>(x, Wa_bf, (void*)w_bf, S1, M, N, K);
  mid_fused<<<dim3(NCH, Bb), dim3(256), 0, stream>>>(w_bf, S1, temp, gamma, pen,
                                                     alpha_f, S2, SA);
  y_phase3<<<dim3(NCH, Bb), dim3(256), 0, stream>>>(w_bf, alpha_f, S2, SA, yprime);
  gemm256<false, false, false><<<gg, gb, 131072, stream>>>(yprime, Wp_bf, (void*)y_out, nullptr, M, N, K);
}

// Round 8
// 253.483 us; speedup vs baseline: 1.0655x; 1.0655x over previous
//
#include <hip/hip_runtime.h>
#include <hip/hip_bf16.h>
#include <stdint.h>

// Problem constants (B,T,D,NH from reference)
#define NHh 16
#define Dm  1024
#define HD  64          // head dim = D/NH
#define Bb  4
#define Tt  4096
#define NCH 128         // chunks along T for the two-pass scans
#define CHL 32          // chunk length (NCH*CHL == Tt)

// 256x256 GEMM tile geometry
#define BM 256
#define BN 256
#define BK 64
#define NKT (Dm / BK)   // 16 K-tiles

using bf16 = __hip_bfloat16;
typedef __attribute__((ext_vector_type(8))) short short8;   // 8 bf16 in 4 VGPRs (MFMA A/B frag)
typedef __attribute__((ext_vector_type(4))) float f32x4;    // MFMA C/D frag

__device__ __forceinline__ float bf2f(bf16 v) { return __bfloat162float(v); }

// bf16 bits -> f32 (exact): bf16 is the high 16 bits of f32
__device__ __forceinline__ float b2f(unsigned short u) {
  union { unsigned int i; float f; } x; x.i = ((unsigned int)u) << 16; return x.f;
}

// fast reciprocal via v_rcp_f32 (~1 ulp; inputs are bf16-derived, tolerance is 1e-2)
__device__ __forceinline__ float frcp(float x) {
  float r; asm("v_rcp_f32 %0, %1" : "=v"(r) : "v"(x)); return r;
}

// async global->LDS, 16B per lane. LDS dest is wave-uniform base + lane*16.
__device__ __forceinline__ void gld_lds16(const void* g, void* l) {
  __builtin_amdgcn_global_load_lds(
      (const __attribute__((address_space(1))) unsigned int*)g,
      (__attribute__((address_space(3))) unsigned int*)l, 16, 0, 0);
}

// ============== 256x256 GEMM, counted-vmcnt 2-phase pipeline =================
// A bf16 via gld_lds (counted 6/2 ledger, round-2 proven loop).
// OUT_BF16: C staged in LDS post-loop (smem dead) + 16B/lane coalesced copy-out
//   — fixes 2x HBM write amplification (measured 69.6 -> 34.8 MB, round 7).
// WRITE_S1: fuse per-32-row chunk sums of bf16(w)^2 into the epilogue.
template <bool OUT_BF16, bool WRITE_S1>
__global__ __launch_bounds__(512, 2) void gemm256(const bf16* __restrict__ A,
                                                  const bf16* __restrict__ W,
                                                  void* __restrict__ Cout,
                                                  float* __restrict__ S1,
                                                  int M, int N, int K) {
  extern __shared__ char smem[];   // 131072 B: [buf][A 32K | B 32K]
  const int tid  = threadIdx.x;
  const int lane = tid & 63;
  const int wave = tid >> 6;       // 0..7
  // T1 XCD swizzle: 256 blocks = 8 XCDs x 32; consecutive swz share the A-panel
  const int bid = blockIdx.x;
  const int swz = (bid & 7) * 32 + (bid >> 3);
  const int bn = (swz & 3) * BN;          // N/BN = 4
  const int bm = (swz >> 2) * BM;
  const int wm = (wave >> 1) * 64;        // 4 M bands of 64 rows
  const int wn = (wave & 1) * 128;        // 2 N halves of 128 cols
  const int quad = lane >> 4;
  const int l16  = lane & 15;

  // staging source (per lane, per slab n): inverse-swizzled global address
  const int srow = wave * 8 + (lane >> 3);               // + n*64
  const int scol = (((lane & 7) ^ (lane >> 3)) << 3);    // elements

  const bf16* Abase = A + (size_t)(bm + srow) * K + scol;
  const bf16* Wbase = W + (size_t)(bn + srow) * K + scol;

  f32x4 acc[4][8] = {};

#define SLAB_A(buf, n) (smem + (buf) * 65536 + (n) * 8192 + wave * 1024)
#define SLAB_B(buf, n) (smem + (buf) * 65536 + 32768 + (n) * 8192 + wave * 1024)
#define STAGE_A(buf, n, k0) gld_lds16(Abase + (size_t)(n) * 64 * K + (k0), SLAB_A(buf, n))
#define STAGE_B(buf, n, k0) gld_lds16(Wbase + (size_t)(n) * 64 * K + (k0), SLAB_B(buf, n))
#define LD_FRAG(base, r, s) (*(const short8*)((base) + (size_t)(r) * 128 + ((((s) ^ ((r) & 7))) << 4)))

  // prologue: stage tile 0 fully into buf 0
  STAGE_A(0, 0, 0); STAGE_A(0, 1, 0); STAGE_A(0, 2, 0); STAGE_A(0, 3, 0);
  STAGE_B(0, 0, 0); STAGE_B(0, 1, 0); STAGE_B(0, 2, 0); STAGE_B(0, 3, 0);
  asm volatile("s_waitcnt vmcnt(0)" ::: "memory");
  __builtin_amdgcn_s_barrier();
  __builtin_amdgcn_sched_barrier(0);

  short8 af[4][2], bfv[4][2];
  for (int t = 0; t < NKT; t++) {
    const int buf = t & 1;
    const char* aL = smem + buf * 65536;
    const char* bL = aL + 32768;
    const int k0n = (t + 1) * BK;
    const bool pf = (t + 1 < NKT);

    // ---- P1: stage 6 slabs (t+1), read A-all + B lower-halves, MFMA nj 0-3
    if (pf) {
      STAGE_A(buf ^ 1, 0, k0n); STAGE_A(buf ^ 1, 1, k0n);
      STAGE_A(buf ^ 1, 2, k0n); STAGE_A(buf ^ 1, 3, k0n);
      STAGE_B(buf ^ 1, 0, k0n); STAGE_B(buf ^ 1, 2, k0n);
    }
#pragma unroll
    for (int mi = 0; mi < 4; mi++) {
      const int r = wm + mi * 16 + l16;
      af[mi][0] = LD_FRAG(aL, r, quad);
      af[mi][1] = LD_FRAG(aL, r, quad + 4);
    }
#pragma unroll
    for (int nj = 0; nj < 4; nj++) {
      const int r = wn + nj * 16 + l16;
      bfv[nj][0] = LD_FRAG(bL, r, quad);
      bfv[nj][1] = LD_FRAG(bL, r, quad + 4);
    }
    __builtin_amdgcn_s_setprio(1);
#pragma unroll
    for (int mi = 0; mi < 4; mi++)
#pragma unroll
      for (int nj = 0; nj < 4; nj++) {
        acc[mi][nj] = __builtin_amdgcn_mfma_f32_16x16x32_bf16(af[mi][0], bfv[nj][0], acc[mi][nj], 0, 0, 0);
        acc[mi][nj] = __builtin_amdgcn_mfma_f32_16x16x32_bf16(af[mi][1], bfv[nj][1], acc[mi][nj], 0, 0, 0);
      }
    __builtin_amdgcn_s_setprio(0);
    if (pf) { asm volatile("s_waitcnt vmcnt(6)" ::: "memory"); }
    else    { asm volatile("s_waitcnt vmcnt(0)" ::: "memory"); }
    __builtin_amdgcn_s_barrier();
    __builtin_amdgcn_sched_barrier(0);

    // ---- P2: stage 2 slabs (t+1), read B upper-halves, MFMA nj 4-7
    if (pf) { STAGE_B(buf ^ 1, 1, k0n); STAGE_B(buf ^ 1, 3, k0n); }
#pragma unroll
    for (int nj = 0; nj < 4; nj++) {
      const int r = wn + 64 + nj * 16 + l16;
      bfv[nj][0] = LD_FRAG(bL, r, quad);
      bfv[nj][1] = LD_FRAG(bL, r, quad + 4);
    }
    __builtin_amdgcn_s_setprio(1);
#pragma unroll
    for (int mi = 0; mi < 4; mi++)
#pragma unroll
      for (int nj = 0; nj < 4; nj++) {
        acc[mi][nj + 4] = __builtin_amdgcn_mfma_f32_16x16x32_bf16(af[mi][0], bfv[nj][0], acc[mi][nj + 4], 0, 0, 0);
        acc[mi][nj + 4] = __builtin_amdgcn_mfma_f32_16x16x32_bf16(af[mi][1], bfv[nj][1], acc[mi][nj + 4], 0, 0, 0);
      }
    __builtin_amdgcn_s_setprio(0);
    asm volatile("s_waitcnt vmcnt(2)" ::: "memory");
    __builtin_amdgcn_s_barrier();
    __builtin_amdgcn_sched_barrier(0);
  }

  // ============ epilogue.  C/D layout: col = lane&15, row = (lane>>4)*4 + reg
  if constexpr (OUT_BF16) {
    // stage C-tile in LDS (smem dead after loop); 16B-chunk XOR swizzle on the
    // scatter writes: byte = row*512 + ((col*2) ^ ((row&7)<<4))
    ushort* cst = (ushort*)smem;
#pragma unroll
    for (int nj = 0; nj < 8; nj++) {
      const int gcol = bn + wn + nj * 16 + l16;
      float ss0 = 0.f, ss1 = 0.f;
#pragma unroll
      for (int mi = 0; mi < 4; mi++) {
        float csum = 0.f;
#pragma unroll
        for (int r = 0; r < 4; r++) {
          const int row = wm + mi * 16 + quad * 4 + r;          // tile-local
          const int col = wn + nj * 16 + l16;                   // tile-local
          const bf16 hv = __float2bfloat16(acc[mi][nj][r]);
          cst[(row * 512 + ((col * 2) ^ ((row & 7) << 4))) >> 1] = __bfloat16_as_ushort(hv);
          if constexpr (WRITE_S1) { const float fv = bf2f(hv); csum += fv * fv; }
        }
        if constexpr (WRITE_S1) { if (mi < 2) ss0 += csum; else ss1 += csum; }
      }
      if constexpr (WRITE_S1) {
        ss0 += __shfl_xor(ss0, 16, 64); ss0 += __shfl_xor(ss0, 32, 64);
        ss1 += __shfl_xor(ss1, 16, 64); ss1 += __shfl_xor(ss1, 32, 64);
        if (quad == 0) {
          const int h = gcol >> 6, d = gcol & 63;
          const int r0 = bm + wm;                    // first row of this wave's band
          const int b  = r0 >> 12;                   // / Tt
          const int c0 = (r0 & (Tt - 1)) >> 5;       // / CHL (=32)
          float* s1p = S1 + (((size_t)(b * NHh + h) * NCH) + c0) * HD + d;
          s1p[0]  = ss0;
          s1p[HD] = ss1;
        }
      }
    }
    asm volatile("s_waitcnt lgkmcnt(0)" ::: "memory");
    __builtin_amdgcn_s_barrier();
    // coalesced copy out: 512 threads x 16B, 16 iters = 128 KB
#pragma unroll
    for (int it = 0; it < 16; it++) {
      const int idx = it * 512 + tid;      // 16B-chunk id (8192 total)
      const int row = idx >> 5;            // 32 chunks per 512B row
      const int ch  = idx & 31;
      const short8 v = *(const short8*)(smem + row * 512 + ((ch ^ (row & 7)) << 4));
      *(short8*)((bf16*)Cout + (size_t)(bm + row) * N + bn + ch * 8) = v;
    }
  } else {
#pragma unroll
    for (int nj = 0; nj < 8; nj++) {
      const int col = bn + wn + nj * 16 + l16;
#pragma unroll
      for (int mi = 0; mi < 4; mi++)
#pragma unroll
        for (int r = 0; r < 4; r++) {
          const int row = bm + wm + mi * 16 + quad * 4 + r;
          ((float*)Cout)[(size_t)row * N + col] = acc[mi][nj][r];
        }
    }
  }
#undef SLAB_A
#undef SLAB_B
#undef STAGE_A
#undef STAGE_B
#undef LD_FRAG
}

// ===== prep: fused {cast x, cast W_attn, cast W_proj, phi->penalty} ==========
__global__ __launch_bounds__(256) void prep(const float* __restrict__ x,
                                            const float* __restrict__ Wa,
                                            const float* __restrict__ Wp,
                                            const float* __restrict__ phi,
                                            bf16* __restrict__ x_bf,
                                            bf16* __restrict__ Wa_bf,
                                            bf16* __restrict__ Wp_bf,
                                            float* __restrict__ penalty) {
  const int bid = blockIdx.x;
  if (bid < 1536) {
    const float* in;
    bf16* out;
    int n, nblk, b0;
    if (bid < 1024)      { in = x;  out = x_bf;  n = Bb * Tt * Dm; nblk = 1024; b0 = 0; }
    else if (bid < 1280) { in = Wa; out = Wa_bf; n = Dm * Dm;      nblk = 256;  b0 = 1024; }
    else                 { in = Wp; out = Wp_bf; n = Dm * Dm;      nblk = 256;  b0 = 1280; }
    const int stride = nblk * 256;
    for (int i = (bid - b0) * 256 + threadIdx.x; i * 4 < n; i += stride) {
      const float4 v = *(const float4*)(in + (size_t)i * 4);
      ushort4 o;
      o.x = __bfloat16_as_ushort(__float2bfloat16(v.x));
      o.y = __bfloat16_as_ushort(__float2bfloat16(v.y));
      o.z = __bfloat16_as_ushort(__float2bfloat16(v.z));
      o.w = __bfloat16_as_ushort(__float2bfloat16(v.w));
      *(ushort4*)(out + (size_t)i * 4) = o;
    }
  } else {
    const int b = bid - 1536;
    const int tid = threadIdx.x;            // 256
    const int lane = tid & 63, wid = tid >> 6;
    __shared__ float wsum[4];
    __shared__ float carry_s;
    if (tid == 0) carry_s = 0.f;
    __syncthreads();
    for (int r = 0; r < Tt / 256; r++) {
      const int t = r * 256 + tid;
      const float v = phi[b * Tt + t];
      float incl = v;
#pragma unroll
      for (int off = 1; off < 64; off <<= 1) {
        float nn = __shfl_up(incl, off, 64);
        if (lane >= off) incl += nn;
      }
      if (lane == 63) wsum[wid] = incl;
      __syncthreads();
      float woff = carry_s;
      for (int wpre = 0; wpre < wid; wpre++) woff += wsum[wpre];
      const float csum = woff + incl;
      const float mean = csum / (float)(t + 1);
      const float dphi = v - mean;
      penalty[b * Tt + t] = dphi * dphi;
      __syncthreads();
      if (tid == 0) carry_s += wsum[0] + wsum[1] + wsum[2] + wsum[3];
      __syncthreads();
    }
  }
}

// ===== fused middle: inline S1 prefix -> tssa -> softmax(heads) -> dots sums =
__global__ __launch_bounds__(256) void mid_fused(const bf16* __restrict__ w,
                                                 const float* __restrict__ S1,
                                                 const float* __restrict__ temp,
                                                 const float* __restrict__ gamma,
                                                 const float* __restrict__ penalty,
                                                 float* __restrict__ alpha_f,
                                                 float* __restrict__ S2,
                                                 float* __restrict__ SA) {
  const int c = blockIdx.x, b = blockIdx.y;
  const int tid = threadIdx.x, h = tid >> 4, l = tid & 15;
  __shared__ float sm_t[CHL][NHh + 1];
  __shared__ float sm_a[CHL][NHh + 1];
  __shared__ float sm_g[NHh], sm_tv[NHh];
  if (tid < NHh) { sm_g[tid] = gamma[tid]; sm_tv[tid] = temp[tid]; }

  // inline exclusive prefix of S1 over chunks < c, 4-deep ILP
  const float4* p4 = (const float4*)(S1 + (((size_t)(b * NHh + h) * NCH)) * HD + l * 4);
  float4 s0 = {0,0,0,0}, s1v = {0,0,0,0}, s2v = {0,0,0,0}, s3v = {0,0,0,0};
  int cc = 0;
  for (; cc + 4 <= c; cc += 4) {
    const float4 v0 = p4[(size_t)cc * 16];
    const float4 v1 = p4[(size_t)(cc + 1) * 16];
    const float4 v2 = p4[(size_t)(cc + 2) * 16];
    const float4 v3 = p4[(size_t)(cc + 3) * 16];
    s0.x += v0.x; s0.y += v0.y; s0.z += v0.z; s0.w += v0.w;
    s1v.x += v1.x; s1v.y += v1.y; s1v.z += v1.z; s1v.w += v1.w;
    s2v.x += v2.x; s2v.y += v2.y; s2v.z += v2.z; s2v.w += v2.w;
    s3v.x += v3.x; s3v.y += v3.y; s3v.z += v3.z; s3v.w += v3.w;
  }
  for (; cc < c; cc++) {
    const float4 v0 = p4[(size_t)cc * 16];
    s0.x += v0.x; s0.y += v0.y; s0.z += v0.z; s0.w += v0.w;
  }
  float a0 = s0.x + s1v.x + s2v.x + s3v.x;
  float a1 = s0.y + s1v.y + s2v.y + s3v.y;
  float a2 = s0.z + s1v.z + s2v.z + s3v.z;
  float a3 = s0.w + s1v.w + s2v.w + s3v.w;
  __syncthreads();   // sm_g/sm_tv ready

  const bf16* wp = w + ((size_t)(b * Tt + c * CHL)) * Dm + h * HD + l * 4;
  const float tv = sm_tv[h];
#pragma unroll 8
  for (int i = 0; i < CHL; i++) {
    const ushort4 v = *(const ushort4*)(wp + (size_t)i * Dm);
    const float f0 = b2f(v.x), f1 = b2f(v.y), f2 = b2f(v.z), f3 = b2f(v.w);
    const float q0 = f0 * f0, q1 = f1 * f1, q2 = f2 * f2, q3 = f3 * f3;
    a0 += q0; a1 += q1; a2 += q2; a3 += q3;
    float val = q0 * frcp(fmaxf(a0, 1e-12f)) + q1 * frcp(fmaxf(a1, 1e-12f))
              + q2 * frcp(fmaxf(a2, 1e-12f)) + q3 * frcp(fmaxf(a3, 1e-12f));
    val += __shfl_xor(val, 1, 64);
    val += __shfl_xor(val, 2, 64);
    val += __shfl_xor(val, 4, 64);
    val += __shfl_xor(val, 8, 64);
    if (l == 0) sm_t[i][h] = tv * val;
  }
  __syncthreads();

  if (tid < CHL) {
    const int t = tid;
    const float pen = penalty[(size_t)b * Tt + c * CHL + t];
    float sc[NHh];
    float mx = -1e30f;
#pragma unroll
    for (int hh = 0; hh < NHh; hh++) {
      sc[hh] = sm_t[t][hh] - sm_g[hh] * pen;
      mx = fmaxf(mx, sc[hh]);
    }
    float sum = 0.f;
#pragma unroll
    for (int hh = 0; hh < NHh; hh++) { const float e = __expf(sc[hh] - mx); sc[hh] = e; sum += e; }
    const float inv = 1.f / sum;
#pragma unroll
    for (int hh = 0; hh < NHh; hh++) sm_a[t][hh] = sc[hh] * inv;
  }
  __syncthreads();

#pragma unroll
  for (int k2 = 0; k2 < CHL / 16; k2++) {
    const int t = k2 * 16 + l;
    alpha_f[((size_t)(b * NHh + h)) * Tt + c * CHL + t] = sm_a[t][h];
  }

  float d0 = 0.f, d1 = 0.f, d2 = 0.f, d3 = 0.f, sa = 0.f;
#pragma unroll 8
  for (int i = 0; i < CHL; i++) {
    const float a = sm_a[i][h];
    const ushort4 v = *(const ushort4*)(wp + (size_t)i * Dm);
    const float f0 = b2f(v.x), f1 = b2f(v.y), f2 = b2f(v.z), f3 = b2f(v.w);
    d0 += f0 * f0 * a; d1 += f1 * f1 * a; d2 += f2 * f2 * a; d3 += f3 * f3 * a;
    sa += a;
  }
  float4 o; o.x = d0; o.y = d1; o.z = d2; o.w = d3;
  *(float4*)&S2[(((size_t)(b * NHh + h) * NCH) + c) * HD + l * 4] = o;
  if (l == 0) SA[(size_t)(b * NHh + h) * NCH + c] = sa;
}

// ===== y': full-row blocks. grid (NCH, Bb), 256 threads = 16 heads x 16 lanes.
__global__ __launch_bounds__(256) void y_phase3(const bf16* __restrict__ w,
                                                const float* __restrict__ alpha_f,
                                                const float* __restrict__ S2,
                                                const float* __restrict__ SA,
                                                bf16* __restrict__ yprime) {
  const int c = blockIdx.x, b = blockIdx.y;
  const int tid = threadIdx.x, h = tid >> 4, l = tid & 15;

  // SA exclusive prefix over chunks < c: lanes split + shfl reduce
  const float* sap = SA + (size_t)(b * NHh + h) * NCH;
  float sa_part = 0.f;
  for (int cc = l; cc < c; cc += 16) sa_part += sap[cc];
  sa_part += __shfl_xor(sa_part, 1, 64);
  sa_part += __shfl_xor(sa_part, 2, 64);
  sa_part += __shfl_xor(sa_part, 4, 64);
  sa_part += __shfl_xor(sa_part, 8, 64);
  float acca = sa_part;   // uniform within the 16-lane group

  // S2 exclusive prefix over chunks < c (own 4 columns), 4-deep ILP
  const float4* p4 = (const float4*)(S2 + (((size_t)(b * NHh + h) * NCH)) * HD + l * 4);
  float4 s0 = {0,0,0,0}, s1v = {0,0,0,0}, s2v = {0,0,0,0}, s3v = {0,0,0,0};
  int cc = 0;
  for (; cc + 4 <= c; cc += 4) {
    const float4 v0 = p4[(size_t)cc * 16];
    const float4 v1 = p4[(size_t)(cc + 1) * 16];
    const float4 v2 = p4[(size_t)(cc + 2) * 16];
    const float4 v3 = p4[(size_t)(cc + 3) * 16];
    s0.x += v0.x; s0.y += v0.y; s0.z += v0.z; s0.w += v0.w;
    s1v.x += v1.x; s1v.y += v1.y; s1v.z += v1.z; s1v.w += v1.w;
    s2v.x += v2.x; s2v.y += v2.y; s2v.z += v2.z; s2v.w += v2.w;
    s3v.x += v3.x; s3v.y += v3.y; s3v.z += v3.z; s3v.w += v3.w;
  }
  for (; cc < c; cc++) {
    const float4 v0 = p4[(size_t)cc * 16];
    s0.x += v0.x; s0.y += v0.y; s0.z += v0.z; s0.w += v0.w;
  }
  float a0 = s0.x + s1v.x + s2v.x + s3v.x;
  float a1 = s0.y + s1v.y + s2v.y + s3v.y;
  float a2 = s0.z + s1v.z + s2v.z + s3v.z;
  float a3 = s0.w + s1v.w + s2v.w + s3v.w;

  const bf16* wp = w + ((size_t)(b * Tt + c * CHL)) * Dm + h * HD + l * 4;
  const float* ap = alpha_f + (size_t)(b * NHh + h) * Tt + c * CHL;
  bf16* yp = yprime + ((size_t)(b * Tt + c * CHL)) * Dm + h * HD + l * 4;
#pragma unroll 8
  for (int i = 0; i < CHL; i++) {
    const float a = ap[i];
    const ushort4 v = *(const ushort4*)(wp + (size_t)i * Dm);
    const float f0 = b2f(v.x), f1 = b2f(v.y), f2 = b2f(v.z), f3 = b2f(v.w);
    a0 += f0 * f0 * a; a1 += f1 * f1 * a; a2 += f2 * f2 * a; a3 += f3 * f3 * a;
    acca += a;
    const float rinv = frcp(acca + 1e-8f);
    const float at0 = fminf(frcp(1.f + a0 * rinv), 10000.f);
    const float at1 = fminf(frcp(1.f + a1 * rinv), 10000.f);
    const float at2 = fminf(frcp(1.f + a2 * rinv), 10000.f);
    const float at3 = fminf(frcp(1.f + a3 * rinv), 10000.f);
    ushort4 o;
    o.x = __bfloat16_as_ushort(__float2bfloat16(-f0 * a * at0));
    o.y = __bfloat16_as_ushort(__float2bfloat16(-f1 * a * at1));
    o.z = __bfloat16_as_ushort(__float2bfloat16(-f2 * a * at2));
    o.w = __bfloat16_as_ushort(__float2bfloat16(-f3 * a * at3));
    *(ushort4*)(yp + (size_t)i * Dm) = o;
  }
}

extern "C" void kernel_launch(void* const* d_in, const int* in_sizes, int n_in,
                              void* d_out, int out_size, void* d_ws, size_t ws_size,
                              hipStream_t stream) {
  const float* x     = (const float*)d_in[0];
  const float* phi   = (const float*)d_in[1];
  const float* Wattn = (const float*)d_in[2];
  const float* Wproj = (const float*)d_in[3];
  const float* gamma = (const float*)d_in[4];
  const float* temp  = (const float*)d_in[5];

  float* y_out    = (float*)d_out;                          // (B,T,D) fp32
  float* alpha_f  = y_out + (size_t)Bb * Tt * Dm;           // (B,NH,T) fp32

  char* ws = (char*)d_ws;
  bf16*  x_bf   = (bf16*)ws;  ws += (size_t)Bb * Tt * Dm * 2;         // 32 MB
  bf16*  Wa_bf  = (bf16*)ws;  ws += (size_t)Dm * Dm * 2;              // 2 MB
  bf16*  Wp_bf  = (bf16*)ws;  ws += (size_t)Dm * Dm * 2;              // 2 MB
  bf16*  w_bf   = (bf16*)ws;  ws += (size_t)Bb * Tt * Dm * 2;         // 32 MB
  float* pen    = (float*)ws; ws += (size_t)Bb * Tt * 4;              // 64 KB
  float* S1     = (float*)ws; ws += (size_t)Bb * NHh * NCH * HD * 4;  // 2 MB (raw)
  float* S2     = (float*)ws; ws += (size_t)Bb * NHh * NCH * HD * 4;  // 2 MB (raw)
  float* SA     = (float*)ws; ws += (size_t)Bb * NHh * NCH * 4;       // 32 KB (raw)
  bf16*  yprime = x_bf;  // alias: x_bf is dead after GEMM1

  static int attr_done = 0;
  if (!attr_done) {
    hipFuncSetAttribute((const void*)gemm256<true, true>,
                        hipFuncAttributeMaxDynamicSharedMemorySize, 131072);
    hipFuncSetAttribute((const void*)gemm256<false, false>,
                        hipFuncAttributeMaxDynamicSharedMemorySize, 131072);
    attr_done = 1;
  }

  const int M = Bb * Tt, N = Dm, K = Dm;
  dim3 gg((M / BM) * (N / BN)), gb(512);

  prep<<<dim3(1540), dim3(256), 0, stream>>>(x, Wattn, Wproj, phi, x_bf, Wa_bf, Wp_bf, pen);
  gemm256<true, true><<<gg, gb, 131072, stream>>>(x_bf, Wa_bf, (void*)w_bf, S1, M, N, K);
  mid_fused<<<dim3(NCH, Bb), dim3(256), 0, stream>>>(w_bf, S1, temp, gamma, pen,
                                                     alpha_f, S2, SA);
  y_phase3<<<dim3(NCH, Bb), dim3(256), 0, stream>>>(w_bf, alpha_f, S2, SA, yprime);
  gemm256<false, false><<<gg, gb, 131072, stream>>>(yprime, Wp_bf, (void*)y_out, nullptr, M, N, K);
}